// Round 4
// baseline (387.787 us; speedup 1.0000x reference)
//
#include <hip/hip_runtime.h>
#include <math.h>

#define TILE_E 16
#define NINS 11
#define IND 288
#define SHD 9
#define W2N 11264
#define YS 165   // ybuf row stride (odd -> conflict-free across e)
#define MS 289   // msg row stride (odd)

typedef _Float16 half8 __attribute__((ext_vector_type(8)));
typedef float f32x4 __attribute__((ext_vector_type(4)));

constexpr int kL1[NINS] = {0,0,0,1,1,1,1,2,2,2,2};
constexpr int kL2[NINS] = {0,1,2,0,1,1,2,0,1,2,2};
constexpr int kL3[NINS] = {0,1,2,1,0,2,1,2,1,0,2};
constexpr int kW3OFF[NINS] = {0,1,10,35,44,53,98,143,168,213,238};

template<int N> struct IC { static constexpr int value = N; };

// ---------------- Wigner 3j on device (exact port of reference, parallel) ----------------
__device__ double dfac(int n){ double r=1.0; for(int i=2;i<=n;++i) r*=(double)i; return r; }

__device__ void qmat_dev(int l,double* qr,double* qi){
  int d=2*l+1;
  for(int i=0;i<d*d;++i){qr[i]=0.0;qi[i]=0.0;}
  const double s=0.70710678118654752440;
  for(int m=-l;m<0;++m){
    qr[(l+m)*d+(l-m)]=s;
    qi[(l+m)*d+(l+m)]=-s;
  }
  qr[l*d+l]=1.0;
  for(int m=1;m<=l;++m){
    double sg=(m&1)?-1.0:1.0;
    qr[(l+m)*d+(l+m)]=sg*s;
    qi[(l+m)*d+(l-m)]=sg*s;
  }
  if(l==1){ for(int i=0;i<d*d;++i){ double a=qr[i],b=qi[i]; qr[i]=b; qi[i]=-a; } }
  else if(l==2){ for(int i=0;i<d*d;++i){ qr[i]=-qr[i]; qi[i]=-qi[i]; } }
}

__global__ __launch_bounds__(128) void w3j_kernel(float* w3j){
  const int ins=blockIdx.x;
  const int l1=kL1[ins],l2=kL2[ins],l3=kL3[ins];
  const int d1=2*l1+1,d2=2*l2+1,d3=2*l3+1;
  const int n=d1*d2*d3;
  const int t=threadIdx.x;

  __shared__ double C[125];
  __shared__ double R[125];
  __shared__ double q1r[25],q1i[25],q2r[25],q2i[25],q3r[25],q3i[25];
  __shared__ double inv;

  for(int i=t;i<125;i+=128) C[i]=0.0;
  if(t==0){
    qmat_dev(l1,q1r,q1i); qmat_dev(l2,q2r,q2i); qmat_dev(l3,q3r,q3i);
  }
  __syncthreads();

  if(t<d1*d2){
    int m1=t/d2-l1, m2=t-(t/d2)*d2-l2;
    int m3=m1+m2;
    if(m3>=-l3 && m3<=l3){
      int vmin=-l1+l2+m3; if(-l1+m1>vmin)vmin=-l1+m1; if(0>vmin)vmin=0;
      int vmax=l2+l3+m1; if(l3-l1+l2<vmax)vmax=l3-l1+l2; if(l3+m3<vmax)vmax=l3+m3;
      double c=sqrt((double)(2*l3+1)*dfac(l3+l1-l2)*dfac(l3-l1+l2)*dfac(l1+l2-l3)
        *dfac(l3+m3)*dfac(l3-m3)
        /(dfac(l1+l2+l3+1)*dfac(l1-m1)*dfac(l1+m1)*dfac(l2-m2)*dfac(l2+m2)));
      double s=0.0;
      for(int v=vmin;v<=vmax;++v){
        double term=dfac(l2+l3+m1-v)*dfac(l1-m1+v)
          /(dfac(v)*dfac(l3-l1+l2-v)*dfac(l3+m3-v)*dfac(v+l1-l2-m3));
        s += (((v+l2+m2)&1)?-1.0:1.0)*term;
      }
      C[((m1+l1)*d2+(m2+l2))*d3+(m3+l3)]=c*s;
    }
  }
  __syncthreads();

  if(t<n){
    int j=t/(d2*d3);
    int rem=t-j*(d2*d3);
    int l=rem/d3, m=rem-l*d3;
    double sr=0.0;
    for(int a=0;a<d1;++a)for(int b=0;b<d2;++b)for(int nn=0;nn<d3;++nn){
      double cv=C[(a*d2+b)*d3+nn];
      if(cv==0.0) continue;
      double xr=q1r[a*d1+j],xi=q1i[a*d1+j];
      double yr=q2r[b*d2+l],yi=q2i[b*d2+l];
      double zr=q3r[nn*d3+m],zi=-q3i[nn*d3+m];
      double pr=xr*yr-xi*yi, pi=xr*yi+xi*yr;
      sr += (pr*zr-pi*zi)*cv;
    }
    R[t]=sr;
  }
  __syncthreads();
  if(t==0){
    double n2=0.0;
    for(int i=0;i<n;++i) n2+=R[i]*R[i];
    inv=1.0/sqrt(n2);
  }
  __syncthreads();
  if(t<n) w3j[kW3OFF[ins]+t]=(float)(R[t]*inv);
}

// ---------------- pack W2 into f16 MFMA A-fragment order (permuted columns) ----------------
// Tile g in [0,704): ins=g>>6, uc=(g>>4)&3, t'=g&15.
// A-row m (=lane&15) maps to orig column: u = uc*8+(m&7), w = t'*2+(m>>3)
//   col = ins*1024 + u*32 + w
// k-step s: lane l elem i holds W2[s*32 + (l>>4)*8 + i][col]
// stored at w2h[((g*2+s)*64 + l)*8 + i]
__global__ __launch_bounds__(256) void pack_w2(const float* __restrict__ W2,
                                               _Float16* __restrict__ w2h){
  int q = blockIdx.x*256 + threadIdx.x;      // 704*2*64 = 90112
  if(q >= 704*2*64) return;
  int l = q & 63;
  int s = (q>>6)&1;
  int g = q>>7;
  int ins=g>>6, rem=g&63, uc=rem>>4, tp=rem&15;
  int m = l&15;
  int col = ins*1024 + (uc*8 + (m&7))*32 + tp*2 + (m>>3);
  int c0  = s*32 + ((l>>4)<<3);
  half8 v;
  #pragma unroll
  for(int i=0;i<8;++i) v[i] = (_Float16)W2[(size_t)(c0+i)*W2N + col];
  *(half8*)&w2h[(size_t)q*8] = v;
}

// ---------------- self connection: out[n] = o3.Linear(x[n]) ----------------
__global__ __launch_bounds__(256) void sc_kernel(const float* __restrict__ x,
  const float* __restrict__ W0, const float* __restrict__ W1s, const float* __restrict__ W2s,
  float* __restrict__ out, int n_nodes)
{
  int n=blockIdx.x;
  if(n>=n_nodes) return;
  const float inv=0.17677669529663689f;  // 1/sqrt(32)
  for(int o=threadIdx.x; o<IND; o+=blockDim.x){
    const float* W; int w,k,d,xo;
    if(o<32){W=W0; w=o; k=0; d=1; xo=0;}
    else if(o<128){int r=o-32; W=W1s; d=3; w=r/3; k=r-w*3; xo=32;}
    else {int r=o-128; W=W2s; d=5; w=r/5; k=r-w*5; xo=128;}
    float s=0.f;
    const float* xr=x+(size_t)n*IND+xo+k;
    for(int u=0;u<32;++u) s += xr[u*d]*W[u*32+w];
    out[(size_t)n*IND+o]=s*inv;
  }
}

// ---------------- fused weight-NN + MFMA tensor product + scatter ----------------
__global__ __launch_bounds__(256,4) void tp_kernel(
    const float* __restrict__ x, const int* __restrict__ eidx,
    const float* __restrict__ sh, const float* __restrict__ radial,
    const float* __restrict__ W1, const _Float16* __restrict__ w2h,
    const float* __restrict__ w3j, float* __restrict__ out,
    int E, float pwc0, float pwc1, float pwc2, float silu_cst)
{
  __shared__ _Float16 h16[TILE_E][64];
  __shared__ float shl[TILE_E][SHD];
  __shared__ float shw[TILE_E][25];
  __shared__ float ybuf[TILE_E][YS];
  __shared__ float msg[TILE_E][MS];
  __shared__ int srcs[TILE_E];
  __shared__ int dsts[TILE_E];

  const int t=threadIdx.x;
  const int e0=blockIdx.x*TILE_E;

  if(t<TILE_E){
    int eg=e0+t;
    srcs[t]= (eg<E)? eidx[eg] : -1;
    dsts[t]= (eg<E)? eidx[E+eg] : -1;
  }
  // h = SILU_CST * silu(radial @ W1 / 8)  -> f16
  for(int idx=t; idx<TILE_E*64; idx+=256){
    int e=idx>>6, c=idx&63;
    int eg=e0+e;
    float hv=0.f;
    if(eg<E){
      const float* rr=radial+(size_t)eg*64;
      float acc=0.f;
      #pragma unroll 8
      for(int r=0;r<64;++r) acc += rr[r]*W1[r*64+c];
      acc*=0.125f;
      hv=silu_cst*acc/(1.f+expf(-acc));
    }
    h16[e][c]=(_Float16)hv;
  }
  for(int idx=t; idx<TILE_E*SHD; idx+=256){
    int e=idx/SHD, j=idx-e*SHD;
    int eg=e0+e;
    shl[e][j]= (eg<E)? sh[(size_t)eg*SHD+j] : 0.f;
  }
  for(int idx=t; idx<TILE_E*MS; idx+=256) msg[idx/MS][idx-(idx/MS)*MS]=0.f;
  __syncthreads();

  const int wv=t>>6, ln=t&63;
  const int eA=ln&15, gA=ln>>4;
  const int upb=(gA&1)*4;
  const int wsel=gA>>1;

  // B fragments (h): lane l holds B[k=(l>>4)*8+i][n=e=l&15]
  half8 hb0 = *(const half8*)&h16[eA][gA*8];
  half8 hb1 = *(const half8*)&h16[eA][32+gA*8];

  const half8* w2p=(const half8*)w2h;

  auto ins_body=[&](auto insC){
    constexpr int INS=decltype(insC)::value;
    constexpr int L1v=kL1[INS], L2v=kL2[INS], L3v=kL3[INS];
    constexpr int D1=2*L1v+1, D2=2*L2v+1, D3=2*L3v+1;
    constexpr int XO=(L1v==0)?0:(L1v==1?32:128);
    constexpr int SO=(L2v==0)?0:(L2v==1?1:4);
    constexpr int OO=(L3v==0)?0:(L3v==1?32:128);
    const float* w3=w3j+kW3OFF[INS];

    // B1: shw[e][i*D3+k] = sum_j w3j[i,j,k]*sh[e,j]
    for(int idx=t; idx<TILE_E*D1*D3; idx+=256){
      int e=idx/(D1*D3), r=idx-e*(D1*D3);
      int i=r/D3, k=r-i*D3;
      float s=0.f;
      #pragma unroll
      for(int j=0;j<D2;++j) s += w3[(i*D2+j)*D3+k]*shl[e][SO+j];
      shw[e][r]=s;
    }
    __syncthreads();
    // B2: ybuf[e][u*D3+k] = sum_i shw[e][i*D3+k] * x[src[e], XO+u*D1+i]
    for(int idx=t; idx<TILE_E*32*D3; idx+=256){
      int e=idx/(32*D3), r=idx-e*(32*D3);
      int u=r/D3, k=r-u*D3;
      float s=0.f;
      int srn=srcs[e];
      if(srn>=0){
        const float* xr=x+(size_t)srn*IND+XO+u*D1;
        #pragma unroll
        for(int i=0;i<D1;++i) s += shw[e][i*D3+k]*xr[i];
      }
      ybuf[e][r]=s;
    }
    __syncthreads();

    float pacc[4][D3];
    #pragma unroll
    for(int q=0;q<4;++q)
      #pragma unroll
      for(int k=0;k<D3;++k) pacc[q][k]=0.f;

    for(int uc=0; uc<4; ++uc){
      // A fragments: 4 tiles x 2 k-steps, coalesced b128 loads (L2-resident)
      const half8* bp = w2p + (size_t)((INS*4+uc)*16 + wv*4)*128 + ln;
      half8 a00=bp[0],   a01=bp[64];
      half8 a10=bp[128], a11=bp[192];
      half8 a20=bp[256], a21=bp[320];
      half8 a30=bp[384], a31=bp[448];
      f32x4 z; z[0]=0.f; z[1]=0.f; z[2]=0.f; z[3]=0.f;
      f32x4 acc0=__builtin_amdgcn_mfma_f32_16x16x32_f16(a00,hb0,z,0,0,0);
      acc0      =__builtin_amdgcn_mfma_f32_16x16x32_f16(a01,hb1,acc0,0,0,0);
      f32x4 acc1=__builtin_amdgcn_mfma_f32_16x16x32_f16(a10,hb0,z,0,0,0);
      acc1      =__builtin_amdgcn_mfma_f32_16x16x32_f16(a11,hb1,acc1,0,0,0);
      f32x4 acc2=__builtin_amdgcn_mfma_f32_16x16x32_f16(a20,hb0,z,0,0,0);
      acc2      =__builtin_amdgcn_mfma_f32_16x16x32_f16(a21,hb1,acc2,0,0,0);
      f32x4 acc3=__builtin_amdgcn_mfma_f32_16x16x32_f16(a30,hb0,z,0,0,0);
      acc3      =__builtin_amdgcn_mfma_f32_16x16x32_f16(a31,hb1,acc3,0,0,0);

      // lane l, tile q, reg j holds wi[e=l&15][u=uc*8+upb+j][w=(wv*4+q)*2+wsel]
      float yv[4][D3];
      #pragma unroll
      for(int j=0;j<4;++j)
        #pragma unroll
        for(int k=0;k<D3;++k)
          yv[j][k]=ybuf[eA][(uc*8+upb+j)*D3+k];
      #pragma unroll
      for(int k=0;k<D3;++k){
        pacc[0][k] += acc0[0]*yv[0][k]+acc0[1]*yv[1][k]+acc0[2]*yv[2][k]+acc0[3]*yv[3][k];
        pacc[1][k] += acc1[0]*yv[0][k]+acc1[1]*yv[1][k]+acc1[2]*yv[2][k]+acc1[3]*yv[3][k];
        pacc[2][k] += acc2[0]*yv[0][k]+acc2[1]*yv[1][k]+acc2[2]*yv[2][k]+acc2[3]*yv[3][k];
        pacc[3][k] += acc3[0]*yv[0][k]+acc3[1]*yv[1][k]+acc3[2]*yv[2][k]+acc3[3]*yv[3][k];
      }
    }
    // butterfly over u-halves (lanes gA and gA^1) + flush to msg (wave-disjoint w ranges)
    const float pw = (L3v==0)?pwc0:((L3v==1)?pwc1:pwc2);
    #pragma unroll
    for(int q=0;q<4;++q){
      #pragma unroll
      for(int k=0;k<D3;++k){
        float p = pacc[q][k] + __shfl_xor(pacc[q][k], 16, 64);
        if((gA&1)==0){
          int w=(wv*4+q)*2 + wsel;
          msg[eA][OO + w*D3 + k] += pw*p;
        }
      }
    }
  };

  ins_body(IC<0>{}); ins_body(IC<1>{}); ins_body(IC<2>{});
  ins_body(IC<3>{}); ins_body(IC<4>{}); ins_body(IC<5>{});
  ins_body(IC<6>{}); ins_body(IC<7>{}); ins_body(IC<8>{});
  ins_body(IC<9>{}); ins_body(IC<10>{});

  __syncthreads();
  // scatter to out[dst]
  for(int idx=t; idx<TILE_E*IND; idx+=256){
    int e=idx/IND, o=idx-e*IND;
    int d=dsts[e];
    if(d>=0) atomicAdd(&out[(size_t)d*IND+o], msg[e][o]);
  }
}

extern "C" void kernel_launch(void* const* d_in, const int* in_sizes, int n_in,
                              void* d_out, int out_size, void* d_ws, size_t ws_size,
                              hipStream_t stream){
  const float* x     =(const float*)d_in[0];
  const int*   eidx  =(const int*)  d_in[1];
  const float* sh    =(const float*)d_in[2];
  const float* radial=(const float*)d_in[3];
  const float* W1    =(const float*)d_in[4];
  const float* W2    =(const float*)d_in[5];
  const float* Wsc0  =(const float*)d_in[6];
  const float* Wsc1  =(const float*)d_in[7];
  const float* Wsc2  =(const float*)d_in[8];
  float* out=(float*)d_out;
  int n_nodes=in_sizes[0]/IND;
  int E=in_sizes[1]/2;

  float inv10=1.0f/sqrtf(10.0f);
  float pwc0=sqrtf(1.0f/96.0f) *0.125f*inv10;
  float pwc1=sqrtf(3.0f/128.0f)*0.125f*inv10;
  float pwc2=sqrtf(5.0f/128.0f)*0.125f*inv10;
  float silu_cst=1.67682f;

  float* w3j=(float*)d_ws;                                  // 363 floats
  _Float16* w2h=(_Float16*)((char*)d_ws + 2048);            // 720896 f16 = 1.41 MB

  hipLaunchKernelGGL(w3j_kernel, dim3(NINS), dim3(128), 0, stream, w3j);
  hipLaunchKernelGGL(pack_w2, dim3(352), dim3(256), 0, stream, W2, w2h);
  hipLaunchKernelGGL(sc_kernel, dim3(n_nodes), dim3(256), 0, stream,
                     x, Wsc0, Wsc1, Wsc2, out, n_nodes);
  hipLaunchKernelGGL(tp_kernel, dim3((E+TILE_E-1)/TILE_E), dim3(256), 0, stream,
                     x, eidx, sh, radial, W1, w2h, w3j, out, E,
                     pwc0, pwc1, pwc2, silu_cst);
}

// Round 5
// 252.064 us; speedup vs baseline: 1.5384x; 1.5384x over previous
//
#include <hip/hip_runtime.h>
#include <math.h>

#define TILE_E 16
#define NINS 11
#define IND 288
#define SHD 9
#define W2N 11264
#define YS 165   // ybuf row stride (odd -> conflict-free across e)
#define MS 289   // msg row stride (odd)

typedef _Float16 half8 __attribute__((ext_vector_type(8)));
typedef float f32x4 __attribute__((ext_vector_type(4)));

constexpr int kL1[NINS] = {0,0,0,1,1,1,1,2,2,2,2};
constexpr int kL2[NINS] = {0,1,2,0,1,1,2,0,1,2,2};
constexpr int kL3[NINS] = {0,1,2,1,0,2,1,2,1,0,2};
constexpr int kW3OFF[NINS] = {0,1,10,35,44,53,98,143,168,213,238};

template<int N> struct IC { static constexpr int value = N; };

// ---------------- Wigner 3j on device (exact port of reference, parallel) ----------------
__device__ double dfac(int n){ double r=1.0; for(int i=2;i<=n;++i) r*=(double)i; return r; }

__device__ void qmat_dev(int l,double* qr,double* qi){
  int d=2*l+1;
  for(int i=0;i<d*d;++i){qr[i]=0.0;qi[i]=0.0;}
  const double s=0.70710678118654752440;
  for(int m=-l;m<0;++m){
    qr[(l+m)*d+(l-m)]=s;
    qi[(l+m)*d+(l+m)]=-s;
  }
  qr[l*d+l]=1.0;
  for(int m=1;m<=l;++m){
    double sg=(m&1)?-1.0:1.0;
    qr[(l+m)*d+(l+m)]=sg*s;
    qi[(l+m)*d+(l-m)]=sg*s;
  }
  if(l==1){ for(int i=0;i<d*d;++i){ double a=qr[i],b=qi[i]; qr[i]=b; qi[i]=-a; } }
  else if(l==2){ for(int i=0;i<d*d;++i){ qr[i]=-qr[i]; qi[i]=-qi[i]; } }
}

__global__ __launch_bounds__(128) void w3j_kernel(float* w3j){
  const int ins=blockIdx.x;
  const int l1=kL1[ins],l2=kL2[ins],l3=kL3[ins];
  const int d1=2*l1+1,d2=2*l2+1,d3=2*l3+1;
  const int n=d1*d2*d3;
  const int t=threadIdx.x;

  __shared__ double C[125];
  __shared__ double R[125];
  __shared__ double q1r[25],q1i[25],q2r[25],q2i[25],q3r[25],q3i[25];
  __shared__ double inv;

  for(int i=t;i<125;i+=128) C[i]=0.0;
  if(t==0){
    qmat_dev(l1,q1r,q1i); qmat_dev(l2,q2r,q2i); qmat_dev(l3,q3r,q3i);
  }
  __syncthreads();

  if(t<d1*d2){
    int m1=t/d2-l1, m2=t-(t/d2)*d2-l2;
    int m3=m1+m2;
    if(m3>=-l3 && m3<=l3){
      int vmin=-l1+l2+m3; if(-l1+m1>vmin)vmin=-l1+m1; if(0>vmin)vmin=0;
      int vmax=l2+l3+m1; if(l3-l1+l2<vmax)vmax=l3-l1+l2; if(l3+m3<vmax)vmax=l3+m3;
      double c=sqrt((double)(2*l3+1)*dfac(l3+l1-l2)*dfac(l3-l1+l2)*dfac(l1+l2-l3)
        *dfac(l3+m3)*dfac(l3-m3)
        /(dfac(l1+l2+l3+1)*dfac(l1-m1)*dfac(l1+m1)*dfac(l2-m2)*dfac(l2+m2)));
      double s=0.0;
      for(int v=vmin;v<=vmax;++v){
        double term=dfac(l2+l3+m1-v)*dfac(l1-m1+v)
          /(dfac(v)*dfac(l3-l1+l2-v)*dfac(l3+m3-v)*dfac(v+l1-l2-m3));
        s += (((v+l2+m2)&1)?-1.0:1.0)*term;
      }
      C[((m1+l1)*d2+(m2+l2))*d3+(m3+l3)]=c*s;
    }
  }
  __syncthreads();

  if(t<n){
    int j=t/(d2*d3);
    int rem=t-j*(d2*d3);
    int l=rem/d3, m=rem-l*d3;
    double sr=0.0;
    for(int a=0;a<d1;++a)for(int b=0;b<d2;++b)for(int nn=0;nn<d3;++nn){
      double cv=C[(a*d2+b)*d3+nn];
      if(cv==0.0) continue;
      double xr=q1r[a*d1+j],xi=q1i[a*d1+j];
      double yr=q2r[b*d2+l],yi=q2i[b*d2+l];
      double zr=q3r[nn*d3+m],zi=-q3i[nn*d3+m];
      double pr=xr*yr-xi*yi, pi=xr*yi+xi*yr;
      sr += (pr*zr-pi*zi)*cv;
    }
    R[t]=sr;
  }
  __syncthreads();
  if(t==0){
    double n2=0.0;
    for(int i=0;i<n;++i) n2+=R[i]*R[i];
    inv=1.0/sqrt(n2);
  }
  __syncthreads();
  if(t<n) w3j[kW3OFF[ins]+t]=(float)(R[t]*inv);
}

// ---------------- pack W2 into f16 MFMA A-fragment order (permuted columns) ----------------
// Tile g in [0,704): ins=g>>6, uc=(g>>4)&3, t'=g&15.
// A-row m (=lane&15) maps to orig column: u = uc*8+(m&7), w = t'*2+(m>>3)
//   col = ins*1024 + u*32 + w
// k-step s: lane l elem i holds W2[s*32 + (l>>4)*8 + i][col]
// stored at w2h[((g*2+s)*64 + l)*8 + i]
__global__ __launch_bounds__(256) void pack_w2(const float* __restrict__ W2,
                                               _Float16* __restrict__ w2h){
  int q = blockIdx.x*256 + threadIdx.x;      // 704*2*64 = 90112
  if(q >= 704*2*64) return;
  int l = q & 63;
  int s = (q>>6)&1;
  int g = q>>7;
  int ins=g>>6, rem=g&63, uc=rem>>4, tp=rem&15;
  int m = l&15;
  int col = ins*1024 + (uc*8 + (m&7))*32 + tp*2 + (m>>3);
  int c0  = s*32 + ((l>>4)<<3);
  half8 v;
  #pragma unroll
  for(int i=0;i<8;++i) v[i] = (_Float16)W2[(size_t)(c0+i)*W2N + col];
  *(half8*)&w2h[(size_t)q*8] = v;
}

// ---------------- self connection: out[n] = o3.Linear(x[n]) ----------------
__global__ __launch_bounds__(256) void sc_kernel(const float* __restrict__ x,
  const float* __restrict__ W0, const float* __restrict__ W1s, const float* __restrict__ W2s,
  float* __restrict__ out, int n_nodes)
{
  int n=blockIdx.x;
  if(n>=n_nodes) return;
  const float inv=0.17677669529663689f;  // 1/sqrt(32)
  for(int o=threadIdx.x; o<IND; o+=blockDim.x){
    const float* W; int w,k,d,xo;
    if(o<32){W=W0; w=o; k=0; d=1; xo=0;}
    else if(o<128){int r=o-32; W=W1s; d=3; w=r/3; k=r-w*3; xo=32;}
    else {int r=o-128; W=W2s; d=5; w=r/5; k=r-w*5; xo=128;}
    float s=0.f;
    const float* xr=x+(size_t)n*IND+xo+k;
    for(int u=0;u<32;++u) s += xr[u*d]*W[u*32+w];
    out[(size_t)n*IND+o]=s*inv;
  }
}

// ---------------- fused weight-NN + MFMA tensor product + scatter ----------------
__global__ __launch_bounds__(256) void tp_kernel(
    const float* __restrict__ x, const int* __restrict__ eidx,
    const float* __restrict__ sh, const float* __restrict__ radial,
    const float* __restrict__ W1, const _Float16* __restrict__ w2h,
    const float* __restrict__ w3j, float* __restrict__ out,
    int E, float pwc0, float pwc1, float pwc2, float silu_cst)
{
  __shared__ _Float16 h16[TILE_E][64];
  __shared__ float shl[TILE_E][SHD];
  __shared__ float shw[TILE_E][25];
  __shared__ float ybuf[TILE_E][YS];
  __shared__ float msg[TILE_E][MS];
  __shared__ int srcs[TILE_E];
  __shared__ int dsts[TILE_E];

  const int t=threadIdx.x;
  const int e0=blockIdx.x*TILE_E;

  if(t<TILE_E){
    int eg=e0+t;
    srcs[t]= (eg<E)? eidx[eg] : -1;
    dsts[t]= (eg<E)? eidx[E+eg] : -1;
  }
  // h = SILU_CST * silu(radial @ W1 / 8)  -> f16
  for(int idx=t; idx<TILE_E*64; idx+=256){
    int e=idx>>6, c=idx&63;
    int eg=e0+e;
    float hv=0.f;
    if(eg<E){
      const float* rr=radial+(size_t)eg*64;
      float acc=0.f;
      #pragma unroll 8
      for(int r=0;r<64;++r) acc += rr[r]*W1[r*64+c];
      acc*=0.125f;
      hv=silu_cst*acc/(1.f+expf(-acc));
    }
    h16[e][c]=(_Float16)hv;
  }
  for(int idx=t; idx<TILE_E*SHD; idx+=256){
    int e=idx/SHD, j=idx-e*SHD;
    int eg=e0+e;
    shl[e][j]= (eg<E)? sh[(size_t)eg*SHD+j] : 0.f;
  }
  for(int idx=t; idx<TILE_E*MS; idx+=256) msg[idx/MS][idx-(idx/MS)*MS]=0.f;
  __syncthreads();

  const int wv=t>>6, ln=t&63;
  const int eA=ln&15, gA=ln>>4;
  const int upb=(gA&1)*4;
  const int wsel=gA>>1;

  // B fragments (h): lane l holds B[k=(l>>4)*8+i][n=e=l&15]
  half8 hb0 = *(const half8*)&h16[eA][gA*8];
  half8 hb1 = *(const half8*)&h16[eA][32+gA*8];

  const half8* w2p=(const half8*)w2h;

  auto ins_body=[&](auto insC){
    constexpr int INS=decltype(insC)::value;
    constexpr int L1v=kL1[INS], L2v=kL2[INS], L3v=kL3[INS];
    constexpr int D1=2*L1v+1, D2=2*L2v+1, D3=2*L3v+1;
    constexpr int XO=(L1v==0)?0:(L1v==1?32:128);
    constexpr int SO=(L2v==0)?0:(L2v==1?1:4);
    constexpr int OO=(L3v==0)?0:(L3v==1?32:128);
    const float* w3=w3j+kW3OFF[INS];
    const float pw = (L3v==0)?pwc0:((L3v==1)?pwc1:pwc2);

    // B1: shw[e][i*D3+k] = sum_j w3j[i,j,k]*sh[e,j]
    for(int idx=t; idx<TILE_E*D1*D3; idx+=256){
      int e=idx/(D1*D3), r=idx-e*(D1*D3);
      int i=r/D3, k=r-i*D3;
      float s=0.f;
      #pragma unroll
      for(int j=0;j<D2;++j) s += w3[(i*D2+j)*D3+k]*shl[e][SO+j];
      shw[e][r]=s;
    }
    __syncthreads();
    // B2: ybuf[e][u*D3+k] = sum_i shw[e][i*D3+k] * x[src[e], XO+u*D1+i]
    for(int idx=t; idx<TILE_E*32*D3; idx+=256){
      int e=idx/(32*D3), r=idx-e*(32*D3);
      int u=r/D3, k=r-u*D3;
      float s=0.f;
      int srn=srcs[e];
      if(srn>=0){
        const float* xr=x+(size_t)srn*IND+XO+u*D1;
        #pragma unroll
        for(int i=0;i<D1;++i) s += shw[e][i*D3+k]*xr[i];
      }
      ybuf[e][r]=s;
    }
    __syncthreads();

    for(int uc=0; uc<4; ++uc){
      // the 4 u-values this lane contracts this pass
      float yv[4][D3];
      #pragma unroll
      for(int j=0;j<4;++j)
        #pragma unroll
        for(int k=0;k<D3;++k)
          yv[j][k]=ybuf[eA][(uc*8+upb+j)*D3+k];

      float pacc[4][D3];
      const half8* bp = w2p + (size_t)((INS*4+uc)*16 + wv*4)*128 + ln;
      #pragma unroll
      for(int q=0;q<4;++q){
        // one q-tile at a time: only 2 A-fragments + 1 accumulator live
        half8 a0=bp[q*128], a1=bp[q*128+64];
        f32x4 z; z[0]=0.f; z[1]=0.f; z[2]=0.f; z[3]=0.f;
        f32x4 acc=__builtin_amdgcn_mfma_f32_16x16x32_f16(a0,hb0,z,0,0,0);
        acc      =__builtin_amdgcn_mfma_f32_16x16x32_f16(a1,hb1,acc,0,0,0);
        // lane l, tile q, reg j holds wi[e=l&15][u=uc*8+upb+j][w=(wv*4+q)*2+wsel]
        #pragma unroll
        for(int k=0;k<D3;++k)
          pacc[q][k] = acc[0]*yv[0][k]+acc[1]*yv[1][k]+acc[2]*yv[2][k]+acc[3]*yv[3][k];
      }
      // butterfly over u-halves (lanes gA, gA^1) + flush (wave-disjoint w ranges)
      #pragma unroll
      for(int q=0;q<4;++q){
        #pragma unroll
        for(int k=0;k<D3;++k){
          float p = pacc[q][k] + __shfl_xor(pacc[q][k], 16, 64);
          if((gA&1)==0){
            int w=(wv*4+q)*2 + wsel;
            msg[eA][OO + w*D3 + k] += pw*p;
          }
        }
      }
    }
  };

  ins_body(IC<0>{}); ins_body(IC<1>{}); ins_body(IC<2>{});
  ins_body(IC<3>{}); ins_body(IC<4>{}); ins_body(IC<5>{});
  ins_body(IC<6>{}); ins_body(IC<7>{}); ins_body(IC<8>{});
  ins_body(IC<9>{}); ins_body(IC<10>{});

  __syncthreads();
  // scatter to out[dst]
  for(int idx=t; idx<TILE_E*IND; idx+=256){
    int e=idx/IND, o=idx-e*IND;
    int d=dsts[e];
    if(d>=0) atomicAdd(&out[(size_t)d*IND+o], msg[e][o]);
  }
}

extern "C" void kernel_launch(void* const* d_in, const int* in_sizes, int n_in,
                              void* d_out, int out_size, void* d_ws, size_t ws_size,
                              hipStream_t stream){
  const float* x     =(const float*)d_in[0];
  const int*   eidx  =(const int*)  d_in[1];
  const float* sh    =(const float*)d_in[2];
  const float* radial=(const float*)d_in[3];
  const float* W1    =(const float*)d_in[4];
  const float* W2    =(const float*)d_in[5];
  const float* Wsc0  =(const float*)d_in[6];
  const float* Wsc1  =(const float*)d_in[7];
  const float* Wsc2  =(const float*)d_in[8];
  float* out=(float*)d_out;
  int n_nodes=in_sizes[0]/IND;
  int E=in_sizes[1]/2;

  float inv10=1.0f/sqrtf(10.0f);
  float pwc0=sqrtf(1.0f/96.0f) *0.125f*inv10;
  float pwc1=sqrtf(3.0f/128.0f)*0.125f*inv10;
  float pwc2=sqrtf(5.0f/128.0f)*0.125f*inv10;
  float silu_cst=1.67682f;

  float* w3j=(float*)d_ws;                                  // 363 floats
  _Float16* w2h=(_Float16*)((char*)d_ws + 2048);            // 720896 f16 = 1.41 MB

  hipLaunchKernelGGL(w3j_kernel, dim3(NINS), dim3(128), 0, stream, w3j);
  hipLaunchKernelGGL(pack_w2, dim3(352), dim3(256), 0, stream, W2, w2h);
  hipLaunchKernelGGL(sc_kernel, dim3(n_nodes), dim3(256), 0, stream,
                     x, Wsc0, Wsc1, Wsc2, out, n_nodes);
  hipLaunchKernelGGL(tp_kernel, dim3((E+TILE_E-1)/TILE_E), dim3(256), 0, stream,
                     x, eidx, sh, radial, W1, w2h, w3j, out, E,
                     pwc0, pwc1, pwc2, silu_cst);
}